// Round 1
// baseline (13396.614 us; speedup 1.0000x reference)
//
#include <hip/hip_runtime.h>

#define T_   500
#define B_   32
#define IN_  512
#define H_   1024
#define KTOT 1536
#define NWG  256
#define NR   32     // gate rows per WG
#define WSTR 1544   // LDS row stride in f16 elems (1536 + 8 pad)

typedef _Float16 f16x8 __attribute__((ext_vector_type(8)));
typedef _Float16 f16x4 __attribute__((ext_vector_type(4)));
typedef float    f32x4 __attribute__((ext_vector_type(4)));

#define MFMA __builtin_amdgcn_mfma_f32_16x16x32_f16

// ---------------------------------------------------------------- grid barrier
__device__ __forceinline__ void gridbar(unsigned* bar, unsigned k) {
  __syncthreads();
  if (threadIdx.x == 0) {
    __threadfence();  // release: flush this XCD's L2 (h writes) to coherence point
    __hip_atomic_fetch_add(bar, 1u, __ATOMIC_RELAXED, __HIP_MEMORY_SCOPE_AGENT);
    const unsigned target = NWG * k;
    int guard = 0;
    while (__hip_atomic_load(bar, __ATOMIC_RELAXED, __HIP_MEMORY_SCOPE_AGENT) < target) {
      __builtin_amdgcn_s_sleep(1);
      if (++guard > (1 << 24)) break;  // co-residency failsafe: fail loud, not hang
    }
    __threadfence();  // acquire: invalidate L1/L2 so fresh h is visible
  }
  __syncthreads();
}

// ---------------------------------------------------------------- x -> fp16
__global__ void cvt_x_kernel(const float* __restrict__ x, _Float16* __restrict__ xb, int n8) {
  int i = blockIdx.x * blockDim.x + threadIdx.x;
  if (i >= n8) return;
  const float4* p = (const float4*)x + (size_t)i * 2;
  float4 v0 = p[0], v1 = p[1];
  f16x8 o = { (_Float16)v0.x, (_Float16)v0.y, (_Float16)v0.z, (_Float16)v0.w,
              (_Float16)v1.x, (_Float16)v1.y, (_Float16)v1.z, (_Float16)v1.w };
  *((f16x8*)xb + i) = o;
}

// ---------------------------------------------------------------- persistent LSTM
__global__ __launch_bounds__(256, 1) void lstm_kernel(
    const float* __restrict__ w_ih_f, const float* __restrict__ w_hh_f,
    const float* __restrict__ b_ih_f, const float* __restrict__ b_hh_f,
    const float* __restrict__ w_ih_r, const float* __restrict__ w_hh_r,
    const float* __restrict__ b_ih_r, const float* __restrict__ b_hh_r,
    const _Float16* __restrict__ xb, _Float16* __restrict__ hb,
    unsigned* __restrict__ bar, float* __restrict__ out)
{
  __shared__ _Float16 Wl[NR * WSTR];   // 98,816 B : [w_ih | w_hh] slice, fp16
  __shared__ float    gl[NR][NR];      //  4,096 B : gate pre-activations

  const int wg   = blockIdx.x;
  const int dir  = wg >> 7;       // 0 = fwd, 1 = rev
  const int slot = wg & 127;
  const int col0 = slot * 8;      // first owned h-column
  const int tid  = threadIdx.x;

  const float* w_ih = dir ? w_ih_r : w_ih_f;
  const float* w_hh = dir ? w_hh_r : w_hh_f;
  const float* b_ih = dir ? b_ih_r : b_ih_f;
  const float* b_hh = dir ? b_hh_r : b_hh_f;

  // ---- stage combined weight slice into LDS as fp16 (rows r=0..31 -> gate row) ----
  for (int i = tid; i < NR * (KTOT / 4); i += 256) {
    int r  = i / (KTOT / 4);
    int k  = (i - r * (KTOT / 4)) * 4;
    int gr = (r >> 3) * H_ + col0 + (r & 7);
    float4 v = (k < IN_) ? *(const float4*)(w_ih + (size_t)gr * IN_ + k)
                         : *(const float4*)(w_hh + (size_t)gr * H_ + (k - IN_));
    f16x4 h4 = { (_Float16)v.x, (_Float16)v.y, (_Float16)v.z, (_Float16)v.w };
    *(f16x4*)(&Wl[r * WSTR + k]) = h4;
  }

  // ---- per-thread (b, h-col) ownership for gates/state ----
  const int tb = tid >> 3, thc = tid & 7, tcol = col0 + thc;
  const float bias0 = b_ih[0 * H_ + tcol] + b_hh[0 * H_ + tcol];
  const float bias1 = b_ih[1 * H_ + tcol] + b_hh[1 * H_ + tcol];
  const float bias2 = b_ih[2 * H_ + tcol] + b_hh[2 * H_ + tcol];
  const float bias3 = b_ih[3 * H_ + tcol] + b_hh[3 * H_ + tcol];
  float c = 0.f;

  const size_t hbase = (size_t)(dir * 2) * B_ * H_;
  // zero h0 (buffer 0), own columns only
  hb[hbase + (size_t)tb * H_ + tcol] = (_Float16)0.f;

  gridbar(bar, 1);   // all weights staged + h0 visible everywhere

  // ---- wave -> MFMA tile assignment ----
  const int lane = tid & 63, wv = tid >> 6;
  const int mh = wv & 1, nh = wv >> 1;       // m-half (batch), n-half (gate rows)
  const int frow = lane & 15, fkb = lane >> 4;
  const int mrow = mh * 16 + frow;           // A row  = batch index
  const int nrow = nh * 16 + frow;           // B row  = local gate row
  const int ko   = fkb * 8;                  // k offset within 32-k step
  const _Float16* bWk = &Wl[nrow * WSTR] + ko;

  for (int s = 0; s < T_; ++s) {
    const int tx = dir ? (T_ - 1 - s) : s;   // time index into x AND output row
    const _Float16* aX = xb + ((size_t)tx * B_ + mrow) * IN_ + ko;
    const _Float16* aH = hb + hbase + (size_t)((s & 1) * B_ + mrow) * H_ + ko;

    f32x4 a0 = {0,0,0,0}, a1 = {0,0,0,0}, a2 = {0,0,0,0}, a3 = {0,0,0,0};
    // x part: K = 0..511
#pragma unroll
    for (int kk = 0; kk < 4; ++kk) {
      a0 = MFMA(*(const f16x8*)(aX + (4*kk+0)*32), *(const f16x8*)(bWk + (4*kk+0)*32), a0, 0,0,0);
      a1 = MFMA(*(const f16x8*)(aX + (4*kk+1)*32), *(const f16x8*)(bWk + (4*kk+1)*32), a1, 0,0,0);
      a2 = MFMA(*(const f16x8*)(aX + (4*kk+2)*32), *(const f16x8*)(bWk + (4*kk+2)*32), a2, 0,0,0);
      a3 = MFMA(*(const f16x8*)(aX + (4*kk+3)*32), *(const f16x8*)(bWk + (4*kk+3)*32), a3, 0,0,0);
    }
    // h part: K = 512..1535
#pragma unroll
    for (int kk = 0; kk < 8; ++kk) {
      a0 = MFMA(*(const f16x8*)(aH + (4*kk+0)*32), *(const f16x8*)(bWk + 512 + (4*kk+0)*32), a0, 0,0,0);
      a1 = MFMA(*(const f16x8*)(aH + (4*kk+1)*32), *(const f16x8*)(bWk + 512 + (4*kk+1)*32), a1, 0,0,0);
      a2 = MFMA(*(const f16x8*)(aH + (4*kk+2)*32), *(const f16x8*)(bWk + 512 + (4*kk+2)*32), a2, 0,0,0);
      a3 = MFMA(*(const f16x8*)(aH + (4*kk+3)*32), *(const f16x8*)(bWk + 512 + (4*kk+3)*32), a3, 0,0,0);
    }
    f32x4 acc = (a0 + a1) + (a2 + a3);

    // D layout (m89-verified): col = lane&15, row = (lane>>4)*4 + reg
#pragma unroll
    for (int i = 0; i < 4; ++i) gl[mh * 16 + fkb * 4 + i][nrow] = acc[i];
    __syncthreads();

    // ---- gates / state update: one thread per (b, h-col) ----
    float xi = gl[tb][ 0 + thc] + bias0;
    float xf = gl[tb][ 8 + thc] + bias1;
    float xg = gl[tb][16 + thc] + bias2;
    float xo = gl[tb][24 + thc] + bias3;
    float ig = fminf(fmaxf(0.2f * xi + 0.5f, 0.f), 1.f);
    float fg = fminf(fmaxf(0.2f * xf + 0.5f, 0.f), 1.f);
    float cg = fminf(fmaxf(xg, -1.f), 1.f);
    float og = fminf(fmaxf(0.2f * xo + 0.5f, 0.f), 1.f);
    c = fg * c + ig * cg;
    float hv = og * fminf(fmaxf(c, -1.f), 1.f);

    out[((size_t)tx * B_ + tb) * (2 * H_) + dir * H_ + tcol] = hv;
    hb[hbase + (size_t)(((s + 1) & 1) * B_ + tb) * H_ + tcol] = (_Float16)hv;

    if (s == T_ - 1) {
      const size_t HY = (size_t)T_ * B_ * 2 * H_;
      out[HY + ((size_t)dir * B_ + tb) * H_ + tcol] = hv;              // hy
      out[HY + (size_t)2 * B_ * H_ + ((size_t)dir * B_ + tb) * H_ + tcol] = c;  // cy
    }
    gridbar(bar, s + 2);   // h(s+1) globally visible; gl safe to overwrite
  }
}

// ---------------------------------------------------------------- launcher
extern "C" void kernel_launch(void* const* d_in, const int* in_sizes, int n_in,
                              void* d_out, int out_size, void* d_ws, size_t ws_size,
                              hipStream_t stream) {
  const float* x      = (const float*)d_in[0];
  const float* w_ih_f = (const float*)d_in[1];
  const float* w_hh_f = (const float*)d_in[2];
  const float* b_ih_f = (const float*)d_in[3];
  const float* b_hh_f = (const float*)d_in[4];
  const float* w_ih_r = (const float*)d_in[5];
  const float* w_hh_r = (const float*)d_in[6];
  const float* b_ih_r = (const float*)d_in[7];
  const float* b_hh_r = (const float*)d_in[8];
  float* out = (float*)d_out;

  char* ws = (char*)d_ws;
  _Float16* xb  = (_Float16*)ws;                        // 16,384,000 B  (T*B*IN f16)
  _Float16* hb  = (_Float16*)(ws + 16384000);           //    262,144 B  (2 dir * 2 buf * B * H f16)
  unsigned* bar = (unsigned*)(ws + 16384000 + 262144);  //        256 B  barrier counter

  hipMemsetAsync(bar, 0, 256, stream);
  cvt_x_kernel<<<4000, 256, 0, stream>>>(x, xb, 1024000);
  lstm_kernel<<<NWG, 256, 0, stream>>>(w_ih_f, w_hh_f, b_ih_f, b_hh_f,
                                       w_ih_r, w_hh_r, b_ih_r, b_hh_r,
                                       xb, hb, bar, out);
}

// Round 2
// 8153.663 us; speedup vs baseline: 1.6430x; 1.6430x over previous
//
#include <hip/hip_runtime.h>

#define T_   500
#define B_   32
#define IN_  512
#define H_   1024
#define KTOT 1536
#define NWG  256
#define NPD  128    // WGs per direction
#define NR   32     // gate rows per WG
#define WSTR 1560   // LDS row stride in f16 elems (1536 + 24 pad -> stride = 12 banks mod 32)

typedef _Float16 f16x8 __attribute__((ext_vector_type(8)));
typedef _Float16 f16x4 __attribute__((ext_vector_type(4)));
typedef float    f32x4 __attribute__((ext_vector_type(4)));

#define MFMA __builtin_amdgcn_mfma_f32_16x16x32_f16

// ---------------------------------------------------------------- x -> fp16
__global__ void cvt_x_kernel(const float* __restrict__ x, _Float16* __restrict__ xb, int n8) {
  int i = blockIdx.x * blockDim.x + threadIdx.x;
  if (i >= n8) return;
  const float4* p = (const float4*)x + (size_t)i * 2;
  float4 v0 = p[0], v1 = p[1];
  f16x8 o = { (_Float16)v0.x, (_Float16)v0.y, (_Float16)v0.z, (_Float16)v0.w,
              (_Float16)v1.x, (_Float16)v1.y, (_Float16)v1.z, (_Float16)v1.w };
  *((f16x8*)xb + i) = o;
}

// ---------------------------------------------------------------- persistent LSTM
__global__ __launch_bounds__(256, 1) void lstm_kernel(
    const float* __restrict__ w_ih_f, const float* __restrict__ w_hh_f,
    const float* __restrict__ b_ih_f, const float* __restrict__ b_hh_f,
    const float* __restrict__ w_ih_r, const float* __restrict__ w_hh_r,
    const float* __restrict__ b_ih_r, const float* __restrict__ b_hh_r,
    const _Float16* __restrict__ xb, _Float16* __restrict__ hb,
    unsigned* __restrict__ flags, float* __restrict__ out)
{
  __shared__ _Float16 Wl[NR * WSTR];   // 99,840 B : [w_ih | w_hh] slice, fp16
  __shared__ float    gl[NR][NR];      //  4,096 B : gate pre-activations

  const int wg   = blockIdx.x;
  const int dir  = wg >> 7;       // 0 = fwd, 1 = rev
  const int slot = wg & 127;
  const int col0 = slot * 8;      // first owned h-column
  const int tid  = threadIdx.x;

  const float* w_ih = dir ? w_ih_r : w_ih_f;
  const float* w_hh = dir ? w_hh_r : w_hh_f;
  const float* b_ih = dir ? b_ih_r : b_ih_f;
  const float* b_hh = dir ? b_hh_r : b_hh_f;

  unsigned* fl = flags + dir * NPD;   // this direction's 128 arrival flags

  // ---- stage combined weight slice into LDS as fp16 (rows r=0..31 -> gate row) ----
  for (int i = tid; i < NR * (KTOT / 4); i += 256) {
    int r  = i / (KTOT / 4);
    int k  = (i - r * (KTOT / 4)) * 4;
    int gr = (r >> 3) * H_ + col0 + (r & 7);
    float4 v = (k < IN_) ? *(const float4*)(w_ih + (size_t)gr * IN_ + k)
                         : *(const float4*)(w_hh + (size_t)gr * H_ + (k - IN_));
    f16x4 h4 = { (_Float16)v.x, (_Float16)v.y, (_Float16)v.z, (_Float16)v.w };
    *(f16x4*)(&Wl[r * WSTR + k]) = h4;
  }

  // ---- per-thread (b, h-col) ownership for gates/state ----
  const int tb = tid >> 3, thc = tid & 7, tcol = col0 + thc;
  const float bias0 = b_ih[0 * H_ + tcol] + b_hh[0 * H_ + tcol];
  const float bias1 = b_ih[1 * H_ + tcol] + b_hh[1 * H_ + tcol];
  const float bias2 = b_ih[2 * H_ + tcol] + b_hh[2 * H_ + tcol];
  const float bias3 = b_ih[3 * H_ + tcol] + b_hh[3 * H_ + tcol];
  float c = 0.f;

  const size_t hbase = (size_t)(dir * 2) * B_ * H_;
  // zero h0 (buffer 0), own columns only
  hb[hbase + (size_t)tb * H_ + tcol] = (_Float16)0.f;

  __syncthreads();                    // weights in LDS + h0 stores drained (vmcnt0 before barrier)
  if (tid == 0) {
    __threadfence();                  // release: h0 visible at coherence point
    __hip_atomic_store(fl + slot, 1u, __ATOMIC_RELAXED, __HIP_MEMORY_SCOPE_AGENT);
  }

  // ---- wave -> MFMA tile assignment ----
  const int lane = tid & 63, wv = tid >> 6;
  const int mh = wv & 1, nh = wv >> 1;       // m-half (batch), n-half (gate rows)
  const int frow = lane & 15, fkb = lane >> 4;
  const int mrow = mh * 16 + frow;           // A row  = batch index
  const int nrow = nh * 16 + frow;           // B row  = local gate row
  const int ko   = fkb * 8;                  // k offset within 32-k step
  const _Float16* bWk = &Wl[nrow * WSTR] + ko;

  for (int s = 0; s < T_; ++s) {
    const int tx = dir ? (T_ - 1 - s) : s;   // time index into x AND output row

    // ================= phase 1: x-part (independent of h) =================
    const _Float16* aX = xb + ((size_t)tx * B_ + mrow) * IN_ + ko;
    f32x4 a0 = {0,0,0,0}, a1 = {0,0,0,0}, a2 = {0,0,0,0}, a3 = {0,0,0,0};
#pragma unroll
    for (int kk = 0; kk < 4; ++kk) {
      a0 = MFMA(*(const f16x8*)(aX + (4*kk+0)*32), *(const f16x8*)(bWk + (4*kk+0)*32), a0, 0,0,0);
      a1 = MFMA(*(const f16x8*)(aX + (4*kk+1)*32), *(const f16x8*)(bWk + (4*kk+1)*32), a1, 0,0,0);
      a2 = MFMA(*(const f16x8*)(aX + (4*kk+2)*32), *(const f16x8*)(bWk + (4*kk+2)*32), a2, 0,0,0);
      a3 = MFMA(*(const f16x8*)(aX + (4*kk+3)*32), *(const f16x8*)(bWk + (4*kk+3)*32), a3, 0,0,0);
    }

    // ================= phase 2: wait for h(s) from all WGs of this dir =====
    if (wv == 0) {
      const unsigned tgt = (unsigned)(s + 1);
      int guard = 0;
      for (;;) {
        unsigned f0 = __hip_atomic_load(fl + lane,      __ATOMIC_RELAXED, __HIP_MEMORY_SCOPE_AGENT);
        unsigned f1 = __hip_atomic_load(fl + 64 + lane, __ATOMIC_RELAXED, __HIP_MEMORY_SCOPE_AGENT);
        if (__all(f0 >= tgt && f1 >= tgt)) break;
        __builtin_amdgcn_s_sleep(1);
        if (++guard > (1 << 22)) break;   // failsafe: fail loud, not hang
      }
      __threadfence();                    // acquire: invalidate L1/L2 so fresh h is visible
    }
    __syncthreads();                      // gate all waves on wave0's poll

    // ================= phase 3: h-part =================
    const _Float16* aH = hb + hbase + (size_t)((s & 1) * B_ + mrow) * H_ + ko;
#pragma unroll
    for (int kk = 0; kk < 8; ++kk) {
      a0 = MFMA(*(const f16x8*)(aH + (4*kk+0)*32), *(const f16x8*)(bWk + 512 + (4*kk+0)*32), a0, 0,0,0);
      a1 = MFMA(*(const f16x8*)(aH + (4*kk+1)*32), *(const f16x8*)(bWk + 512 + (4*kk+1)*32), a1, 0,0,0);
      a2 = MFMA(*(const f16x8*)(aH + (4*kk+2)*32), *(const f16x8*)(bWk + 512 + (4*kk+2)*32), a2, 0,0,0);
      a3 = MFMA(*(const f16x8*)(aH + (4*kk+3)*32), *(const f16x8*)(bWk + 512 + (4*kk+3)*32), a3, 0,0,0);
    }
    f32x4 acc = (a0 + a1) + (a2 + a3);

    // D layout (m89-verified): col = lane&15, row = (lane>>4)*4 + reg
#pragma unroll
    for (int i = 0; i < 4; ++i) gl[mh * 16 + fkb * 4 + i][nrow] = acc[i];
    __syncthreads();

    // ================= phase 4: gates / state update =================
    float xi = gl[tb][ 0 + thc] + bias0;
    float xf = gl[tb][ 8 + thc] + bias1;
    float xg = gl[tb][16 + thc] + bias2;
    float xo = gl[tb][24 + thc] + bias3;
    float ig = fminf(fmaxf(0.2f * xi + 0.5f, 0.f), 1.f);
    float fg = fminf(fmaxf(0.2f * xf + 0.5f, 0.f), 1.f);
    float cg = fminf(fmaxf(xg, -1.f), 1.f);
    float og = fminf(fmaxf(0.2f * xo + 0.5f, 0.f), 1.f);
    c = fg * c + ig * cg;
    float hv = og * fminf(fmaxf(c, -1.f), 1.f);

    out[((size_t)tx * B_ + tb) * (2 * H_) + dir * H_ + tcol] = hv;
    hb[hbase + (size_t)(((s + 1) & 1) * B_ + tb) * H_ + tcol] = (_Float16)hv;

    if (s == T_ - 1) {
      const size_t HY = (size_t)T_ * B_ * 2 * H_;
      out[HY + ((size_t)dir * B_ + tb) * H_ + tcol] = hv;              // hy
      out[HY + (size_t)2 * B_ * H_ + ((size_t)dir * B_ + tb) * H_ + tcol] = c;  // cy
    }

    // ================= phase 5: arrive (h(s+1) published) =================
    __syncthreads();                      // all threads' h stores drained to L2
    if (tid == 0) {
      __threadfence();                    // L2 writeback to coherence point
      __hip_atomic_store(fl + slot, (unsigned)(s + 2), __ATOMIC_RELAXED, __HIP_MEMORY_SCOPE_AGENT);
    }
    // no wait here: next iteration's x-part overlaps flag propagation
  }
}

// ---------------------------------------------------------------- launcher
extern "C" void kernel_launch(void* const* d_in, const int* in_sizes, int n_in,
                              void* d_out, int out_size, void* d_ws, size_t ws_size,
                              hipStream_t stream) {
  const float* x      = (const float*)d_in[0];
  const float* w_ih_f = (const float*)d_in[1];
  const float* w_hh_f = (const float*)d_in[2];
  const float* b_ih_f = (const float*)d_in[3];
  const float* b_hh_f = (const float*)d_in[4];
  const float* w_ih_r = (const float*)d_in[5];
  const float* w_hh_r = (const float*)d_in[6];
  const float* b_ih_r = (const float*)d_in[7];
  const float* b_hh_r = (const float*)d_in[8];
  float* out = (float*)d_out;

  char* ws = (char*)d_ws;
  _Float16* xb    = (_Float16*)ws;                        // 16,384,000 B  (T*B*IN f16)
  _Float16* hb    = (_Float16*)(ws + 16384000);           //    262,144 B  (2 dir * 2 buf * B * H f16)
  unsigned* flags = (unsigned*)(ws + 16384000 + 262144);  //      1,024 B  (2 dir * 128 arrival flags)

  hipMemsetAsync(flags, 0, 1024, stream);
  cvt_x_kernel<<<4000, 256, 0, stream>>>(x, xb, 1024000);
  lstm_kernel<<<NWG, 256, 0, stream>>>(w_ih_f, w_hh_f, b_ih_f, b_hh_f,
                                       w_ih_r, w_hh_r, b_ih_r, b_hh_r,
                                       xb, hb, flags, out);
}

// Round 3
// 2354.968 us; speedup vs baseline: 5.6887x; 3.4623x over previous
//
#include <hip/hip_runtime.h>

#define T_   500
#define B_   32
#define IN_  512
#define H_   1024
#define KTOT 1536
#define NWG  256
#define NPD  128    // WGs per direction
#define NR   32     // gate rows per WG
#define WSTR 1544   // LDS row stride in f16 elems (dword-stride 772 === 4 mod 32 -> 2-way max on b128)

typedef _Float16 f16x8 __attribute__((ext_vector_type(8)));
typedef _Float16 f16x4 __attribute__((ext_vector_type(4)));
typedef float    f32x4 __attribute__((ext_vector_type(4)));

#define MFMA __builtin_amdgcn_mfma_f32_16x16x32_f16

// counted vmem wait + scheduling fence (rule #18: MFMA hoists past bare asm waitcnt)
#define WAITV(N) do { asm volatile("s_waitcnt vmcnt(" #N ")" ::: "memory"); \
                      __builtin_amdgcn_sched_barrier(0); } while (0)

// coherent (MALL) 16B load: bypasses L1/L2 so no acquire-invalidate is needed
#define HLOAD(r, J) \
  asm volatile("global_load_dwordx4 %0, %1, off offset:%2 sc0 sc1" \
               : "=v"(hf##r) : "v"(aH), "i"(128 * ((J) - 8)) : "memory")

#define HMFMA(r, J) do { \
  p0[(J) & 1] = MFMA(hf##r, *(const f16x8*)(bW0 + 64 * (J)), p0[(J) & 1], 0, 0, 0); \
  p1[(J) & 1] = MFMA(hf##r, *(const f16x8*)(bW1 + 64 * (J)), p1[(J) & 1], 0, 0, 0); } while (0)

// ---------------------------------------------------------------- x -> fp16
__global__ void cvt_x_kernel(const float* __restrict__ x, _Float16* __restrict__ xb, int n8) {
  int i = blockIdx.x * blockDim.x + threadIdx.x;
  if (i >= n8) return;
  const float4* p = (const float4*)x + (size_t)i * 2;
  float4 v0 = p[0], v1 = p[1];
  f16x8 o = { (_Float16)v0.x, (_Float16)v0.y, (_Float16)v0.z, (_Float16)v0.w,
              (_Float16)v1.x, (_Float16)v1.y, (_Float16)v1.z, (_Float16)v1.w };
  *((f16x8*)xb + i) = o;
}

// ---------------------------------------------------------------- persistent LSTM
__global__ __launch_bounds__(256, 1) void lstm_kernel(
    const float* __restrict__ w_ih_f, const float* __restrict__ w_hh_f,
    const float* __restrict__ b_ih_f, const float* __restrict__ b_hh_f,
    const float* __restrict__ w_ih_r, const float* __restrict__ w_hh_r,
    const float* __restrict__ b_ih_r, const float* __restrict__ b_hh_r,
    const _Float16* __restrict__ xb, _Float16* __restrict__ hb,
    unsigned* __restrict__ flags, float* __restrict__ out)
{
  __shared__ _Float16 Wl[NR * WSTR];        // 98,816 B : [w_ih | w_hh] slice, fp16
  __shared__ float glA[NR][NR + 1];         //  4,224 B : partial gates, K-half 0
  __shared__ float glB[NR][NR + 1];         //  4,224 B : partial gates, K-half 1

  const int wg   = blockIdx.x;
  const int dir  = wg >> 7;
  const int slot = wg & 127;
  const int col0 = slot * 8;
  const int tid  = threadIdx.x;

  const float* w_ih = dir ? w_ih_r : w_ih_f;
  const float* w_hh = dir ? w_hh_r : w_hh_f;
  const float* b_ih = dir ? b_ih_r : b_ih_f;
  const float* b_hh = dir ? b_hh_r : b_hh_f;

  unsigned* fl = flags + dir * NPD;

  // ---- stage combined weight slice into LDS as fp16 ----
  for (int i = tid; i < NR * (KTOT / 4); i += 256) {
    int r  = i / (KTOT / 4);
    int k  = (i - r * (KTOT / 4)) * 4;
    int gr = (r >> 3) * H_ + col0 + (r & 7);
    float4 v = (k < IN_) ? *(const float4*)(w_ih + (size_t)gr * IN_ + k)
                         : *(const float4*)(w_hh + (size_t)gr * H_ + (k - IN_));
    f16x4 h4 = { (_Float16)v.x, (_Float16)v.y, (_Float16)v.z, (_Float16)v.w };
    *(f16x4*)(&Wl[r * WSTR + k]) = h4;
  }

  // ---- per-thread (b, h-col) ownership ----
  const int tb = tid >> 3, thc = tid & 7, tcol = col0 + thc;
  const float bias0 = b_ih[0 * H_ + tcol] + b_hh[0 * H_ + tcol];
  const float bias1 = b_ih[1 * H_ + tcol] + b_hh[1 * H_ + tcol];
  const float bias2 = b_ih[2 * H_ + tcol] + b_hh[2 * H_ + tcol];
  const float bias3 = b_ih[3 * H_ + tcol] + b_hh[3 * H_ + tcol];
  float c = 0.f;

  const size_t hbase = (size_t)(dir * 2) * B_ * H_;
  { // h0 = 0, coherent store (write-through to MALL)
    const _Float16* hp = hb + hbase + (size_t)tb * H_ + tcol;
    unsigned z = 0;
    asm volatile("global_store_short %0, %1, off sc0 sc1" :: "v"(hp), "v"(z) : "memory");
  }
  asm volatile("s_waitcnt vmcnt(0)" ::: "memory");
  __syncthreads();
  if (tid == 0)
    __hip_atomic_store(fl + slot, 1u, __ATOMIC_RELAXED, __HIP_MEMORY_SCOPE_AGENT);

  // ---- wave tiling: wave w = (m-half, K-parity) ; each wave does BOTH n-tiles ----
  const int lane = tid & 63, wv = tid >> 6;
  const int mh = wv & 1, kh = wv >> 1;       // m-half (batch), K-interleave parity
  const int frow = lane & 15, fkb = lane >> 4;
  const int mrow = mh * 16 + frow;           // batch row this lane supplies
  // k-step for slice j (j=0..23): ks = 2j + kh ; elem offset = 64j + 32kh + 8fkb
  const int kbase = 32 * kh + 8 * fkb;
  const _Float16* bW0 = &Wl[frow * WSTR + kbase];          // n-tile 0 (rows 0..15)
  const _Float16* bW1 = &Wl[(16 + frow) * WSTR + kbase];   // n-tile 1 (rows 16..31)

  for (int s = 0; s < T_; ++s) {
    const int tx = dir ? (T_ - 1 - s) : s;

    // ===== phase 1: x-part (j = 0..7, K 0..511 interleaved) — cached loads =====
    const _Float16* aX = xb + ((size_t)tx * B_ + mrow) * IN_ + kbase;
    f32x4 p0[2] = {{0,0,0,0},{0,0,0,0}}, p1[2] = {{0,0,0,0},{0,0,0,0}};
#pragma unroll
    for (int j = 0; j < 8; ++j) {
      f16x8 xf = *(const f16x8*)(aX + 64 * j);
      p0[j & 1] = MFMA(xf, *(const f16x8*)(bW0 + 64 * j), p0[j & 1], 0, 0, 0);
      p1[j & 1] = MFMA(xf, *(const f16x8*)(bW1 + 64 * j), p1[j & 1], 0, 0, 0);
    }

    // ===== phase 2: wait for h(s) published by all WGs of this direction =====
    if (wv == 0) {
      const unsigned tgt = (unsigned)(s + 1);
      int guard = 0;
      for (;;) {
        unsigned f0 = __hip_atomic_load(fl + lane,      __ATOMIC_RELAXED, __HIP_MEMORY_SCOPE_AGENT);
        unsigned f1 = __hip_atomic_load(fl + 64 + lane, __ATOMIC_RELAXED, __HIP_MEMORY_SCOPE_AGENT);
        if (__all(f0 >= tgt && f1 >= tgt)) break;
        __builtin_amdgcn_s_sleep(1);
        if (++guard > (1 << 22)) break;   // failsafe: fail loud, not hang
      }
    }
    __syncthreads();

    // ===== phase 3: h-part (j = 8..23), coherent loads, depth-2 pipelined =====
    const _Float16* aH = hb + hbase + (size_t)((s & 1) * B_ + mrow) * H_ + kbase;
    f16x8 hf0, hf1, hf2, hf3, hf4, hf5, hf6, hf7;
    WAITV(0);                                  // insurance: clean vmcnt baseline
    HLOAD(0,  8); HLOAD(1,  9); HLOAD(2, 10); HLOAD(3, 11);
    HLOAD(4, 12); HLOAD(5, 13); HLOAD(6, 14); HLOAD(7, 15);
    WAITV(4);
    HMFMA(0,  8); HMFMA(1,  9); HMFMA(2, 10); HMFMA(3, 11);
    HLOAD(0, 16); HLOAD(1, 17); HLOAD(2, 18); HLOAD(3, 19);
    WAITV(4);
    HMFMA(4, 12); HMFMA(5, 13); HMFMA(6, 14); HMFMA(7, 15);
    HLOAD(4, 20); HLOAD(5, 21); HLOAD(6, 22); HLOAD(7, 23);
    WAITV(4);
    HMFMA(0, 16); HMFMA(1, 17); HMFMA(2, 18); HMFMA(3, 19);
    WAITV(0);
    HMFMA(4, 20); HMFMA(5, 21); HMFMA(6, 22); HMFMA(7, 23);

    f32x4 an0 = p0[0] + p0[1];
    f32x4 an1 = p1[0] + p1[1];

    // D layout (m89): col = lane&15 (n), row = (lane>>4)*4 + reg (m)
    float* gld = kh ? &glB[0][0] : &glA[0][0];
    const int grow = mh * 16 + fkb * 4;
#pragma unroll
    for (int i = 0; i < 4; ++i) {
      gld[(grow + i) * (NR + 1) + frow]      = an0[i];
      gld[(grow + i) * (NR + 1) + 16 + frow] = an1[i];
    }
    __syncthreads();

    // ===== phase 4: gates / state update =====
    float xi = glA[tb][ 0 + thc] + glB[tb][ 0 + thc] + bias0;
    float xf_ = glA[tb][ 8 + thc] + glB[tb][ 8 + thc] + bias1;
    float xg = glA[tb][16 + thc] + glB[tb][16 + thc] + bias2;
    float xo = glA[tb][24 + thc] + glB[tb][24 + thc] + bias3;
    float ig = fminf(fmaxf(0.2f * xi + 0.5f, 0.f), 1.f);
    float fg = fminf(fmaxf(0.2f * xf_ + 0.5f, 0.f), 1.f);
    float cg = fminf(fmaxf(xg, -1.f), 1.f);
    float og = fminf(fmaxf(0.2f * xo + 0.5f, 0.f), 1.f);
    c = fg * c + ig * cg;
    float hv = og * fminf(fmaxf(c, -1.f), 1.f);

    out[((size_t)tx * B_ + tb) * (2 * H_) + dir * H_ + tcol] = hv;
    { // coherent h publish (write-through to MALL, no L2 flush needed)
      const _Float16* hp = hb + hbase + (size_t)(((s + 1) & 1) * B_ + tb) * H_ + tcol;
      unsigned hbits = (unsigned)__builtin_bit_cast(unsigned short, (_Float16)hv);
      asm volatile("global_store_short %0, %1, off sc0 sc1" :: "v"(hp), "v"(hbits) : "memory");
    }
    if (s == T_ - 1) {
      const size_t HY = (size_t)T_ * B_ * 2 * H_;
      out[HY + ((size_t)dir * B_ + tb) * H_ + tcol] = hv;                           // hy
      out[HY + (size_t)2 * B_ * H_ + ((size_t)dir * B_ + tb) * H_ + tcol] = c;      // cy
    }

    // ===== phase 5: release + arrive (no wbl2: stores were write-through) =====
    asm volatile("s_waitcnt vmcnt(0)" ::: "memory");   // own h store ack'd at MALL
    __syncthreads();                                   // all threads ack'd
    if (tid == 0)
      __hip_atomic_store(fl + slot, (unsigned)(s + 2), __ATOMIC_RELAXED, __HIP_MEMORY_SCOPE_AGENT);
  }
}

// ---------------------------------------------------------------- launcher
extern "C" void kernel_launch(void* const* d_in, const int* in_sizes, int n_in,
                              void* d_out, int out_size, void* d_ws, size_t ws_size,
                              hipStream_t stream) {
  const float* x      = (const float*)d_in[0];
  const float* w_ih_f = (const float*)d_in[1];
  const float* w_hh_f = (const float*)d_in[2];
  const float* b_ih_f = (const float*)d_in[3];
  const float* b_hh_f = (const float*)d_in[4];
  const float* w_ih_r = (const float*)d_in[5];
  const float* w_hh_r = (const float*)d_in[6];
  const float* b_ih_r = (const float*)d_in[7];
  const float* b_hh_r = (const float*)d_in[8];
  float* out = (float*)d_out;

  char* ws = (char*)d_ws;
  _Float16* xb    = (_Float16*)ws;                        // 16,384,000 B
  _Float16* hb    = (_Float16*)(ws + 16384000);           //    262,144 B
  unsigned* flags = (unsigned*)(ws + 16384000 + 262144);  //      1,024 B

  hipMemsetAsync(flags, 0, 1024, stream);
  cvt_x_kernel<<<4000, 256, 0, stream>>>(x, xb, 1024000);
  lstm_kernel<<<NWG, 256, 0, stream>>>(w_ih_f, w_hh_f, b_ih_f, b_hh_f,
                                       w_ih_r, w_hh_r, b_ih_r, b_hh_r,
                                       xb, hb, flags, out);
}